// Round 3
// baseline (40.574 us; speedup 1.0000x reference)
//
#include <hip/hip_runtime.h>

// B=8, X=Y=Z=128, f32. Periodic 7-point Laplacian of (mu*active), times active.
#define NB 8
#define NX 128
#define NY 128
#define NZ 128

#define TY 8             // y-rows per block
#define TX 8             // x-planes per block
#define XC (NX / TX)     // 16 x-chunks
#define YT (NY / TY)     // 16 y-tiles
#define PLANE_ROWS (TY + 2)

__global__ __launch_bounds__(256) void lap_lds(
    const float* __restrict__ mu,
    const float* __restrict__ act,
    const float* __restrict__ dxp,
    float* __restrict__ out)
{
    // e = mu*act ring buffer: 3 x-planes of (TY+2) y-rows x 128 z
    __shared__ float e[3][PLANE_ROWS][NZ];   // 15360 B

    const int tid = threadIdx.x;
    const int bid = blockIdx.x;
    const int xc = bid & (XC - 1);
    const int yt = (bid >> 4) & (YT - 1);
    const int b  = bid >> 8;

    const int x0 = xc * TX;
    const int y0 = yt * TY;
    const int planeYZ = NY * NZ;           // 16384
    const int baseB = b * NX * planeYZ;

    const float dxv = dxp[0];
    const float inv = 1.0f / (dxv * dxv);

    const int r  = tid >> 5;     // 0..7
    const int zq = tid & 31;
    const int z0 = zq * 4;

    float4 A;    // act for the plane currently being computed (this thread's point)
    float4 Bt;   // act for the plane just loaded

    // load plane at global x = gx into ring slot `slot`; keep center act in keepA
    auto load_plane = [&](int gx, int slot, float4* keepA) {
        const int px = baseB + gx * planeYZ;
        {
            const int gIdx = px + (y0 + r) * NZ + z0;
            float4 m = *reinterpret_cast<const float4*>(mu + gIdx);
            float4 a = *reinterpret_cast<const float4*>(act + gIdx);
            *keepA = a;
            float4 ev = make_float4(m.x * a.x, m.y * a.y, m.z * a.z, m.w * a.w);
            *reinterpret_cast<float4*>(&e[slot][r + 1][z0]) = ev;
        }
        if (tid < 64) {
            const int hr = tid >> 5;           // 0: y-1 halo, 1: y+TY halo
            const int hzq = tid & 31;
            const int gy = hr ? ((y0 + TY) & (NY - 1)) : ((y0 - 1) & (NY - 1));
            const int lr = hr ? (TY + 1) : 0;
            const int gIdx = px + gy * NZ + hzq * 4;
            float4 m = *reinterpret_cast<const float4*>(mu + gIdx);
            float4 a = *reinterpret_cast<const float4*>(act + gIdx);
            float4 ev = make_float4(m.x * a.x, m.y * a.y, m.z * a.z, m.w * a.w);
            *reinterpret_cast<float4*>(&e[slot][lr][hzq * 4]) = ev;
        }
    };

    // slot(lp) = (lp+1) % 3 for local plane lp in [-1, TX]
    load_plane((x0 - 1) & (NX - 1), 0, &Bt);   // lp=-1 halo (act discarded)
    load_plane(x0, 1, &A);                      // lp=0

    for (int i = 0; i < TX; ++i) {
        const int sm = i % 3;            // slot(i-1)
        const int sc = (i + 1) % 3;      // slot(i)
        const int sp = (i + 2) % 3;      // slot(i+1)

        load_plane((x0 + i + 1) & (NX - 1), sp, &Bt);   // lp=i+1
        __syncthreads();

        const int gx = x0 + i;           // in [x0, x0+TX), no wrap needed
        const int px = baseB + gx * planeYZ;
        {
            float4 ec  = *reinterpret_cast<const float4*>(&e[sc][r + 1][z0]);
            float4 exm = *reinterpret_cast<const float4*>(&e[sm][r + 1][z0]);
            float4 exP = *reinterpret_cast<const float4*>(&e[sp][r + 1][z0]);
            float4 eym = *reinterpret_cast<const float4*>(&e[sc][r][z0]);
            float4 eyp = *reinterpret_cast<const float4*>(&e[sc][r + 2][z0]);
            float ezm = e[sc][r + 1][(z0 - 1) & (NZ - 1)];
            float ezp = e[sc][r + 1][(z0 + 4) & (NZ - 1)];
            float4 o;
            o.x = (exm.x + exP.x + eym.x + eyp.x + ezm + ec.y - 6.0f * ec.x) * inv * A.x;
            o.y = (exm.y + exP.y + eym.y + eyp.y + ec.x + ec.z - 6.0f * ec.y) * inv * A.y;
            o.z = (exm.z + exP.z + eym.z + eyp.z + ec.y + ec.w - 6.0f * ec.z) * inv * A.z;
            o.w = (exm.w + exP.w + eym.w + eyp.w + ec.z + ezp - 6.0f * ec.w) * inv * A.w;
            const int gIdx = px + (y0 + r) * NZ + z0;
            *reinterpret_cast<float4*>(out + gIdx) = o;
        }

        A = Bt;
        __syncthreads();   // before next load overwrites slot sm
    }
}

extern "C" void kernel_launch(void* const* d_in, const int* in_sizes, int n_in,
                              void* d_out, int out_size, void* d_ws, size_t ws_size,
                              hipStream_t stream) {
    const float* mu  = (const float*)d_in[0];
    const float* act = (const float*)d_in[1];
    const float* dx  = (const float*)d_in[2];
    float* out = (float*)d_out;

    const int grid = NB * YT * XC;   // 2048 blocks
    lap_lds<<<grid, 256, 0, stream>>>(mu, act, dx, out);
}

// Round 4
// 36.103 us; speedup vs baseline: 1.1238x; 1.1238x over previous
//
#include <hip/hip_runtime.h>

// B=8, X=Y=Z=128, f32. out = active * Lap(mu*active) / dx^2, periodic.
// Register-marching 2.5D: thread owns (y, z0..z0+3) column, marches x.
#define NB 8
#define NX 128
#define NY 128
#define NZ 128

#define TY 16
#define TX 16
#define XC (NX / TX)     // 8
#define YT (NY / TY)     // 8
#define ROWS (TY + 2)    // 18

__global__ __launch_bounds__(512) void lap_march(
    const float* __restrict__ mu,
    const float* __restrict__ act,
    const float* __restrict__ dxp,
    float* __restrict__ out)
{
    __shared__ float buf[2][ROWS][NZ];   // 18432 B, double-buffered e-planes

    const int tid = threadIdx.x;         // 0..511
    const int bid = blockIdx.x;
    const int xc = bid & (XC - 1);
    const int yt = (bid >> 3) & (YT - 1);
    const int b  = bid >> 6;

    const int x0 = xc * TX;
    const int y0 = yt * TY;
    const int planeYZ = NY * NZ;         // 16384
    const int baseB = b * NX * planeYZ;

    const float dxv = dxp[0];
    const float inv = 1.0f / (dxv * dxv);

    const int r  = tid >> 5;             // 0..15 (y row within tile)
    const int zq = tid & 31;
    const int z0 = zq * 4;
    const int gy = y0 + r;

    float4 eP, eC, eN, aC, aN;

    auto ldE = [&](int gx, float4* ev, float4* av) {
        const int gIdx = baseB + gx * planeYZ + gy * NZ + z0;
        float4 m = *reinterpret_cast<const float4*>(mu + gIdx);
        float4 a = *reinterpret_cast<const float4*>(act + gIdx);
        *av = a;
        *ev = make_float4(m.x * a.x, m.y * a.y, m.z * a.z, m.w * a.w);
    };

    auto ldHalo = [&](int gx, int slot) {
        // 2 y-halo rows x 32 z-quads, done by wave 0
        if (tid < 64) {
            const int hr = tid >> 5;               // 0: y-1, 1: y+TY
            const int hz = (tid & 31) * 4;
            const int hy = hr ? ((y0 + TY) & (NY - 1)) : ((y0 - 1) & (NY - 1));
            const int gIdx = baseB + gx * planeYZ + hy * NZ + hz;
            float4 m = *reinterpret_cast<const float4*>(mu + gIdx);
            float4 a = *reinterpret_cast<const float4*>(act + gIdx);
            *reinterpret_cast<float4*>(&buf[slot][hr ? TY + 1 : 0][hz]) =
                make_float4(m.x * a.x, m.y * a.y, m.z * a.z, m.w * a.w);
        }
    };

    // prologue: eP = plane x0-1 (regs only), eC/buf[0] = plane x0
    {
        float4 dummy;
        ldE((x0 - 1) & (NX - 1), &eP, &dummy);
        ldE(x0, &eC, &aC);
        *reinterpret_cast<float4*>(&buf[0][r + 1][z0]) = eC;
        ldHalo(x0, 0);
    }
    __syncthreads();

    for (int i = 0; i < TX; ++i) {
        // load plane x0+i+1 -> eN regs; to LDS buf[(i+1)&1] unless it's the
        // reg-only exit halo plane (i == TX-1)
        const int gxn = (x0 + i + 1) & (NX - 1);
        ldE(gxn, &eN, &aN);
        if (i < TX - 1) {
            *reinterpret_cast<float4*>(&buf[(i + 1) & 1][r + 1][z0]) = eN;
            ldHalo(gxn, (i + 1) & 1);
        }

        // compute plane x0+i from regs + buf[i&1]
        const int s = i & 1;
        float4 eym = *reinterpret_cast<const float4*>(&buf[s][r][z0]);
        float4 eyp = *reinterpret_cast<const float4*>(&buf[s][r + 2][z0]);
        float ezm = __shfl(eC.w, (zq + 31) & 31, 32);  // z0-1 (periodic in 32-group)
        float ezp = __shfl(eC.x, (zq + 1) & 31, 32);   // z0+4

        float4 o;
        o.x = (eP.x + eN.x + eym.x + eyp.x + ezm  + eC.y - 6.0f * eC.x) * inv * aC.x;
        o.y = (eP.y + eN.y + eym.y + eyp.y + eC.x + eC.z - 6.0f * eC.y) * inv * aC.y;
        o.z = (eP.z + eN.z + eym.z + eyp.z + eC.y + eC.w - 6.0f * eC.z) * inv * aC.z;
        o.w = (eP.w + eN.w + eym.w + eyp.w + eC.z + ezp  - 6.0f * eC.w) * inv * aC.w;

        const int gIdx = baseB + (x0 + i) * planeYZ + gy * NZ + z0;
        *reinterpret_cast<float4*>(out + gIdx) = o;

        eP = eC; eC = eN; aC = aN;
        __syncthreads();   // one barrier per plane (protects both buffers)
    }
}

extern "C" void kernel_launch(void* const* d_in, const int* in_sizes, int n_in,
                              void* d_out, int out_size, void* d_ws, size_t ws_size,
                              hipStream_t stream) {
    const float* mu  = (const float*)d_in[0];
    const float* act = (const float*)d_in[1];
    const float* dx  = (const float*)d_in[2];
    float* out = (float*)d_out;

    const int grid = NB * YT * XC;   // 512 blocks
    lap_march<<<grid, 512, 0, stream>>>(mu, act, dx, out);
}